// Round 2
// baseline (1438.727 us; speedup 1.0000x reference)
//
#include <hip/hip_runtime.h>

typedef __attribute__((ext_vector_type(8))) short short8;
typedef __attribute__((ext_vector_type(4))) float f32x4;
typedef __attribute__((ext_vector_type(4))) unsigned short us4;
typedef unsigned short u16;

__device__ __forceinline__ u16 f2bf(float f) {
    unsigned u = __builtin_bit_cast(unsigned, f);
    return (u16)((u + 0x7fffu + ((u >> 16) & 1u)) >> 16);
}
__device__ __forceinline__ float bf2f(u16 h) {
    unsigned u = ((unsigned)h) << 16;
    return __builtin_bit_cast(float, u);
}
__device__ __forceinline__ void async16(const void* g, void* l) {
    __builtin_amdgcn_global_load_lds((const __attribute__((address_space(1))) unsigned int*)g,
                                     (__attribute__((address_space(3))) unsigned int*)l,
                                     16, 0, 0);
}

// ---------------- elementwise fp32 -> bf16 conversion ----------------
__global__ __launch_bounds__(256) void cvt_k(const float* __restrict__ in, u16* __restrict__ out) {
    int i = (blockIdx.x * 256 + threadIdx.x) * 4;
    f32x4 v = *(const f32x4*)(in + i);
    us4 o;
    o[0] = f2bf(v[0]); o[1] = f2bf(v[1]); o[2] = f2bf(v[2]); o[3] = f2bf(v[3]);
    *(us4*)(out + i) = o;
}

// ---------------- rmsnorm (keeps source bug: MULTIPLY by sqrt(var+eps)) ----------------
__global__ __launch_bounds__(256) void rmsnorm_k(const float* __restrict__ X, const float* __restrict__ g,
                                                 u16* __restrict__ O) {
    const int row = blockIdx.x, tid = threadIdx.x;
    const float* xr = X + (long)row * 2048 + tid * 8;
    f32x4 v0 = *(const f32x4*)xr;
    f32x4 v1 = *(const f32x4*)(xr + 4);
    float ss = v0[0]*v0[0] + v0[1]*v0[1] + v0[2]*v0[2] + v0[3]*v0[3]
             + v1[0]*v1[0] + v1[1]*v1[1] + v1[2]*v1[2] + v1[3]*v1[3];
#pragma unroll
    for (int m = 1; m < 64; m <<= 1) ss += __shfl_xor(ss, m, 64);
    __shared__ float wsum[4];
    if ((tid & 63) == 0) wsum[tid >> 6] = ss;
    __syncthreads();
    float tot = wsum[0] + wsum[1] + wsum[2] + wsum[3];
    const float sc = sqrtf(tot * (1.0f / 2048.0f) + 1e-6f);
    const float* gr = g + tid * 8;
    f32x4 g0 = *(const f32x4*)gr, g1 = *(const f32x4*)(gr + 4);
    us4 o0, o1;
    o0[0] = f2bf(v0[0] * sc * g0[0]); o0[1] = f2bf(v0[1] * sc * g0[1]);
    o0[2] = f2bf(v0[2] * sc * g0[2]); o0[3] = f2bf(v0[3] * sc * g0[3]);
    o1[0] = f2bf(v1[0] * sc * g1[0]); o1[1] = f2bf(v1[1] * sc * g1[1]);
    o1[2] = f2bf(v1[2] * sc * g1[2]); o1[3] = f2bf(v1[3] * sc * g1[3]);
    u16* op = O + (long)row * 2048 + tid * 8;
    *(us4*)op = o0;
    *(us4*)(op + 4) = o1;
}

// ---------------- generic C = A * W^T GEMM (bf16 in, fp32 acc), m97 structure ----------------
// A: [M][K] bf16 row-major; W: [N][K] bf16 row-major. 128x128 tile, BK=32, 256 thr = 4 waves.
// NOTE: aux/resid/out may ALIAS out (in-place epilogues) -> no __restrict__ on them.
enum { M_QKV = 0, M_VT = 1, M_H1 = 2, M_RELU = 3, M_MUL = 4, M_ADD = 5 };

template <int MODE>
__global__ __launch_bounds__(256) void gemm_bt(const u16* __restrict__ A, const u16* __restrict__ W,
                                               const float* __restrict__ bias, const float* resid,
                                               const u16* aux, void* out,
                                               int N, int K, float scale) {
    __shared__ u16 As[128 * 32];
    __shared__ u16 Bs[128 * 32];
    const int tid = threadIdx.x, wv = tid >> 6, lane = tid & 63;
    const int q4 = lane >> 4, lr = lane & 15;
    const long m0 = (long)blockIdx.y * 128;
    const int n0 = blockIdx.x * 128;
    const int wm = (wv >> 1) * 64, wn = (wv & 1) * 64;
    f32x4 acc[4][4] = {};

    const int r0 = tid >> 2, b0 = (tid & 3) * 8;   // chunk -> (row, elem offset)
    const int r1 = 64 + r0;
    u16* lA0 = As + (wv * 64) * 8;
    u16* lA1 = As + (256 + wv * 64) * 8;
    u16* lB0 = Bs + (wv * 64) * 8;
    u16* lB1 = Bs + (256 + wv * 64) * 8;
    const u16* a0 = A + (m0 + r0) * (long)K + b0;
    const u16* a1 = A + (m0 + r1) * (long)K + b0;
    const u16* w0 = W + (long)(n0 + r0) * K + b0;
    const u16* w1 = W + (long)(n0 + r1) * K + b0;

    for (int k0 = 0; k0 < K; k0 += 32) {
        __syncthreads();
        async16(a0 + k0, lA0);
        async16(a1 + k0, lA1);
        async16(w0 + k0, lB0);
        async16(w1 + k0, lB1);
        __syncthreads();
        short8 af[4], bf[4];
#pragma unroll
        for (int i = 0; i < 4; i++) af[i] = *(const short8*)(As + (wm + i * 16 + lr) * 32 + q4 * 8);
#pragma unroll
        for (int j = 0; j < 4; j++) bf[j] = *(const short8*)(Bs + (wn + j * 16 + lr) * 32 + q4 * 8);
#pragma unroll
        for (int i = 0; i < 4; i++)
#pragma unroll
            for (int j = 0; j < 4; j++)
                acc[i][j] = __builtin_amdgcn_mfma_f32_16x16x32_bf16(af[i], bf[j], acc[i][j], 0, 0, 0);
    }

    // epilogue: C row = quad*4+reg, col = lane&15
#pragma unroll
    for (int i = 0; i < 4; i++) {
#pragma unroll
        for (int j = 0; j < 4; j++) {
            const int gn = n0 + wn + j * 16 + lr;
#pragma unroll
            for (int r = 0; r < 4; r++) {
                const long gm = m0 + wm + i * 16 + q4 * 4 + r;
                float v = acc[i][j][r];
                if constexpr (MODE == M_QKV) {
                    v = (v + bias[gn]) * scale;
                    ((u16*)out)[gm * N + gn] = f2bf(v);
                } else if constexpr (MODE == M_VT) {
                    v = v + bias[gm];
                    const long b = gn >> 11, s = gn & 2047;
                    ((u16*)out)[(b << 22) + gm * 2048 + s] = f2bf(v);
                } else if constexpr (MODE == M_H1) {
                    ((float*)out)[gm * N + gn] = v + bias[gn] + resid[gm * N + gn];
                } else if constexpr (MODE == M_RELU) {
                    ((u16*)out)[gm * N + gn] = f2bf(fmaxf(v, 0.0f));
                } else if constexpr (MODE == M_MUL) {
                    ((u16*)out)[gm * N + gn] = f2bf(v * bf2f(aux[gm * N + gn]));
                } else {  // M_ADD
                    ((float*)out)[gm * N + gn] = v + resid[gm * N + gn];
                }
            }
        }
    }
}

// ---------------- flash attention, computes O^T directly into the scrambled layout ----------------
// Q,K: [4096][2048] bf16 (rows b*2048+s, head slice at h*128). Vt: [b][h*128+d][s] bf16.
// Out scr[b][h*128+d][s] = softmax(QK^T/sqrt(128)) @ V, transposed. Scale folded into Q.
__global__ __launch_bounds__(512) void attn_kernel(const u16* __restrict__ Q, const u16* __restrict__ Km,
                                                   const u16* __restrict__ Vt, u16* __restrict__ Oscr) {
    __shared__ u16 Ks[128 * 128];
    __shared__ u16 Vs[128 * 128];
    __shared__ u16 Ps[8][16 * 136];  // per-wave P strip, pitch 136 (2-way-only bank aliasing)
    __shared__ float abuf[8][16];
    __shared__ float lbuf[8][16];
    const int tid = threadIdx.x, w = tid >> 6, lane = tid & 63;
    const int q4 = lane >> 4, lr = lane & 15;
    const int bh = blockIdx.y, b = bh >> 4, h = bh & 15;
    const int sw = blockIdx.x * 128 + w * 16;  // this wave's 16 query rows
    const long qkbase = ((long)b * 2048) * 2048 + h * 128;
    const long vtbase = ((long)b * 2048 + h * 128) * 2048;

    short8 qf[4];
    {
        const u16* qr = Q + qkbase + (long)(sw + lr) * 2048 + q4 * 8;
#pragma unroll
        for (int kk = 0; kk < 4; kk++) qf[kk] = *(const short8*)(qr + kk * 32);
    }
    float m_i[4], l_i[4];
#pragma unroll
    for (int r = 0; r < 4; r++) { m_i[r] = -1e30f; l_i[r] = 0.0f; }
    f32x4 oacc[8] = {};

    for (int t0 = 0; t0 < 2048; t0 += 128) {
        __syncthreads();
#pragma unroll
        for (int i = 0; i < 4; i++) {
            const int c = i * 512 + tid;
            const int row = c >> 4, cb = (c & 15) * 8;
            async16(Km + qkbase + (long)(t0 + row) * 2048 + cb, (u16*)Ks + (i * 512 + w * 64) * 8);
            async16(Vt + vtbase + (long)row * 2048 + t0 + cb, (u16*)Vs + (i * 512 + w * 64) * 8);
        }
        __syncthreads();
        // S strip [16 s][128 t] = q * K^T (scale pre-folded into q)
        f32x4 sacc[8] = {};
#pragma unroll
        for (int kk = 0; kk < 4; kk++) {
#pragma unroll
            for (int n = 0; n < 8; n++) {
                short8 kf = *(const short8*)(Ks + (n * 16 + lr) * 128 + kk * 32 + q4 * 8);
                sacc[n] = __builtin_amdgcn_mfma_f32_16x16x32_bf16(qf[kk], kf, sacc[n], 0, 0, 0);
            }
        }
        // online softmax per s-row (row = q4*4+r, replicated across the 16 lanes of the quad)
        float al[4];
#pragma unroll
        for (int r = 0; r < 4; r++) {
            float mx = sacc[0][r];
#pragma unroll
            for (int n = 1; n < 8; n++) mx = fmaxf(mx, sacc[n][r]);
#pragma unroll
            for (int msk = 1; msk < 16; msk <<= 1) mx = fmaxf(mx, __shfl_xor(mx, msk, 64));
            const float mn = fmaxf(m_i[r], mx);
            al[r] = __expf(m_i[r] - mn);
            float rs = 0.0f;
#pragma unroll
            for (int n = 0; n < 8; n++) {
                float p = __expf(sacc[n][r] - mn);
                sacc[n][r] = p;
                rs += p;
            }
#pragma unroll
            for (int msk = 1; msk < 16; msk <<= 1) rs += __shfl_xor(rs, msk, 64);
            l_i[r] = l_i[r] * al[r] + rs;
            m_i[r] = mn;
        }
        // P -> LDS (bf16), alpha broadcast
#pragma unroll
        for (int n = 0; n < 8; n++)
#pragma unroll
            for (int r = 0; r < 4; r++)
                Ps[w][(q4 * 4 + r) * 136 + n * 16 + lr] = f2bf(sacc[n][r]);
        if (lr == 0) {
#pragma unroll
            for (int r = 0; r < 4; r++) abuf[w][q4 * 4 + r] = al[r];
        }
        __syncthreads();
        const float a_s = abuf[w][lr];
#pragma unroll
        for (int mm = 0; mm < 8; mm++) oacc[mm] *= a_s;
        // O^T[d][s] += Vt_tile(rows d) * P^T : A-frag from Vs rows, B-frag from Ps rows
#pragma unroll
        for (int kk = 0; kk < 4; kk++) {
            short8 pf = *(const short8*)(&Ps[w][lr * 136 + kk * 32 + q4 * 8]);
#pragma unroll
            for (int mm = 0; mm < 8; mm++) {
                short8 vf = *(const short8*)(Vs + (mm * 16 + lr) * 128 + kk * 32 + q4 * 8);
                oacc[mm] = __builtin_amdgcn_mfma_f32_16x16x32_bf16(vf, pf, oacc[mm], 0, 0, 0);
            }
        }
    }
    if (lr == 0) {
#pragma unroll
        for (int r = 0; r < 4; r++) lbuf[w][q4 * 4 + r] = l_i[r];
    }
    __syncthreads();
    const float linv = 1.0f / lbuf[w][lr];
    // write O^T: row d = mm*16+q4*4+r, col s = sw+lr (16-lane contiguous bf16 stores)
#pragma unroll
    for (int mm = 0; mm < 8; mm++) {
#pragma unroll
        for (int r = 0; r < 4; r++) {
            const int d = mm * 16 + q4 * 4 + r;
            Oscr[vtbase + (long)d * 2048 + sw + lr] = f2bf(oacc[mm][r] * linv);
        }
    }
}

// ---------------- launch ----------------
// Workspace budget (112 MB total), lifetime-aliased:
//   [0,16)MB   : xn  -> scr -> hn      (sequential lives)
//   [16,80)MB  : qb|kb|vt (16 each, qb at 16, kb at 32, vt at 48)
//                -> grelu (64) -> inter (in-place with grelu)
//   [80,112)MB : JIT bf16 weight region: {wq,wk,wv,wo} -> wg -> wu -> wd
//   h1 lives in d_out (fp32, fully overwritten before first read).
extern "C" void kernel_launch(void* const* d_in, const int* in_sizes, int n_in,
                              void* d_out, int out_size, void* d_ws, size_t ws_size,
                              hipStream_t stream) {
    const float* x  = (const float*)d_in[0];
    const float* wq = (const float*)d_in[1];
    const float* bq = (const float*)d_in[2];
    const float* wk = (const float*)d_in[3];
    const float* bk = (const float*)d_in[4];
    const float* wv = (const float*)d_in[5];
    const float* bv = (const float*)d_in[6];
    const float* wo = (const float*)d_in[7];
    const float* bo = (const float*)d_in[8];
    const float* wg = (const float*)d_in[9];
    const float* wu = (const float*)d_in[10];
    const float* wd = (const float*)d_in[11];
    const float* ga = (const float*)d_in[12];
    const float* gf = (const float*)d_in[13];

    char* ws = (char*)d_ws;
    const size_t MB = (size_t)1 << 20;
    u16*  xn    = (u16*)(ws + 0);
    u16*  scr   = (u16*)(ws + 0);            // alias: xn dead after projections
    u16*  hn    = (u16*)(ws + 0);            // alias: scr dead after o-proj
    u16*  qb    = (u16*)(ws + 16 * MB);
    u16*  kb    = (u16*)(ws + 32 * MB);
    u16*  vt    = (u16*)(ws + 48 * MB);
    u16*  grelu = (u16*)(ws + 16 * MB);      // 64 MB, alias over qb/kb/vt/pad
    u16*  inter = grelu;                     // in-place relu(g)*u
    u16*  wreg  = (u16*)(ws + 80 * MB);      // 32 MB JIT weight region
    u16*  wq_b  = wreg;
    u16*  wk_b  = wreg + 4 * MB;             // u16 elements: 8MB bytes each
    u16*  wv_b  = wreg + 8 * MB;
    u16*  wo_b  = wreg + 12 * MB;
    u16*  wbig  = wreg;                      // wg -> wu -> wd reuse
    float* h1   = (float*)d_out;

    // phase-A weights fp32 -> bf16
    cvt_k<<<4096, 256, 0, stream>>>(wq, wq_b);
    cvt_k<<<4096, 256, 0, stream>>>(wk, wk_b);
    cvt_k<<<4096, 256, 0, stream>>>(wv, wv_b);
    cvt_k<<<4096, 256, 0, stream>>>(wo, wo_b);

    rmsnorm_k<<<4096, 256, 0, stream>>>(x, ga, xn);

    const float qscale = 0.08838834764831843f;  // 1/sqrt(128)
    gemm_bt<M_QKV><<<dim3(16, 32), 256, 0, stream>>>(xn, wq_b, bq, nullptr, nullptr, qb, 2048, 2048, qscale);
    gemm_bt<M_QKV><<<dim3(16, 32), 256, 0, stream>>>(xn, wk_b, bk, nullptr, nullptr, kb, 2048, 2048, 1.0f);
    // V^T: roles swapped -> C[nv][(b,s)] = wv . xn^T, stored [b][nv][s]
    gemm_bt<M_VT><<<dim3(32, 16), 256, 0, stream>>>(wv_b, xn, bv, nullptr, nullptr, vt, 4096, 2048, 1.0f);

    attn_kernel<<<dim3(16, 32), 512, 0, stream>>>(qb, kb, vt, scr);

    // out-proj + residual: h1 = x + scr @ wo^T + bo   (h1 lives in d_out)
    gemm_bt<M_H1><<<dim3(16, 32), 256, 0, stream>>>(scr, wo_b, bo, x, nullptr, h1, 2048, 2048, 1.0f);

    cvt_k<<<16384, 256, 0, stream>>>(wg, wbig);          // wq..wo dead now
    rmsnorm_k<<<4096, 256, 0, stream>>>(h1, gf, hn);

    gemm_bt<M_RELU><<<dim3(64, 32), 256, 0, stream>>>(hn, wbig, nullptr, nullptr, nullptr, grelu, 8192, 2048, 1.0f);

    cvt_k<<<16384, 256, 0, stream>>>(wu, wbig);          // wg dead
    gemm_bt<M_MUL><<<dim3(64, 32), 256, 0, stream>>>(hn, wbig, nullptr, nullptr, grelu, inter, 8192, 2048, 1.0f);

    cvt_k<<<16384, 256, 0, stream>>>(wd, wbig);          // wu dead
    gemm_bt<M_ADD><<<dim3(16, 32), 256, 0, stream>>>(inter, wbig, nullptr, h1, nullptr, d_out, 2048, 8192, 1.0f);
}

// Round 3
// 1259.212 us; speedup vs baseline: 1.1426x; 1.1426x over previous
//
#include <hip/hip_runtime.h>

typedef __attribute__((ext_vector_type(8))) short short8;
typedef __attribute__((ext_vector_type(4))) float f32x4;
typedef __attribute__((ext_vector_type(4))) unsigned short us4;
typedef unsigned short u16;

__device__ __forceinline__ u16 f2bf(float f) {
    unsigned u = __builtin_bit_cast(unsigned, f);
    return (u16)((u + 0x7fffu + ((u >> 16) & 1u)) >> 16);
}
__device__ __forceinline__ float bf2f(u16 h) {
    unsigned u = ((unsigned)h) << 16;
    return __builtin_bit_cast(float, u);
}
__device__ __forceinline__ void async16(const void* g, void* l) {
    __builtin_amdgcn_global_load_lds((const __attribute__((address_space(1))) unsigned int*)g,
                                     (__attribute__((address_space(3))) unsigned int*)l,
                                     16, 0, 0);
}

// ---------------- elementwise fp32 -> bf16 conversion ----------------
__global__ __launch_bounds__(256) void cvt_k(const float* __restrict__ in, u16* __restrict__ out) {
    int i = (blockIdx.x * 256 + threadIdx.x) * 4;
    f32x4 v = *(const f32x4*)(in + i);
    us4 o;
    o[0] = f2bf(v[0]); o[1] = f2bf(v[1]); o[2] = f2bf(v[2]); o[3] = f2bf(v[3]);
    *(us4*)(out + i) = o;
}

// ---------------- rmsnorm (keeps source bug: MULTIPLY by sqrt(var+eps)) ----------------
__global__ __launch_bounds__(256) void rmsnorm_k(const float* __restrict__ X, const float* __restrict__ g,
                                                 u16* __restrict__ O) {
    const int row = blockIdx.x, tid = threadIdx.x;
    const float* xr = X + (long)row * 2048 + tid * 8;
    f32x4 v0 = *(const f32x4*)xr;
    f32x4 v1 = *(const f32x4*)(xr + 4);
    float ss = v0[0]*v0[0] + v0[1]*v0[1] + v0[2]*v0[2] + v0[3]*v0[3]
             + v1[0]*v1[0] + v1[1]*v1[1] + v1[2]*v1[2] + v1[3]*v1[3];
#pragma unroll
    for (int m = 1; m < 64; m <<= 1) ss += __shfl_xor(ss, m, 64);
    __shared__ float wsum[4];
    if ((tid & 63) == 0) wsum[tid >> 6] = ss;
    __syncthreads();
    float tot = wsum[0] + wsum[1] + wsum[2] + wsum[3];
    const float sc = sqrtf(tot * (1.0f / 2048.0f) + 1e-6f);
    const float* gr = g + tid * 8;
    f32x4 g0 = *(const f32x4*)gr, g1 = *(const f32x4*)(gr + 4);
    us4 o0, o1;
    o0[0] = f2bf(v0[0] * sc * g0[0]); o0[1] = f2bf(v0[1] * sc * g0[1]);
    o0[2] = f2bf(v0[2] * sc * g0[2]); o0[3] = f2bf(v0[3] * sc * g0[3]);
    o1[0] = f2bf(v1[0] * sc * g1[0]); o1[1] = f2bf(v1[1] * sc * g1[1]);
    o1[2] = f2bf(v1[2] * sc * g1[2]); o1[3] = f2bf(v1[3] * sc * g1[3]);
    u16* op = O + (long)row * 2048 + tid * 8;
    *(us4*)op = o0;
    *(us4*)(op + 4) = o1;
}

// ---------------- generic C = A * W^T GEMM (bf16 in, fp32 acc), m97 structure ----------------
// A: [M][K] bf16 row-major; W: [N][K] bf16 row-major. 128x128 tile, BK=32, 256 thr = 4 waves.
// NOTE: aux/resid/out may ALIAS out (in-place epilogues) -> no __restrict__ on them.
enum { M_QKV = 0, M_VT = 1, M_H1 = 2, M_RELU = 3, M_MUL = 4, M_ADD = 5 };

template <int MODE>
__global__ __launch_bounds__(256) void gemm_bt(const u16* __restrict__ A, const u16* __restrict__ W,
                                               const float* __restrict__ bias, const float* resid,
                                               const u16* aux, void* out,
                                               int N, int K, float scale) {
    __shared__ u16 As[128 * 32];
    __shared__ u16 Bs[128 * 32];
    const int tid = threadIdx.x, wv = tid >> 6, lane = tid & 63;
    const int q4 = lane >> 4, lr = lane & 15;
    const long m0 = (long)blockIdx.y * 128;
    const int n0 = blockIdx.x * 128;
    const int wm = (wv >> 1) * 64, wn = (wv & 1) * 64;
    f32x4 acc[4][4] = {};

    const int r0 = tid >> 2, b0 = (tid & 3) * 8;   // chunk -> (row, elem offset)
    const int r1 = 64 + r0;
    u16* lA0 = As + (wv * 64) * 8;
    u16* lA1 = As + (256 + wv * 64) * 8;
    u16* lB0 = Bs + (wv * 64) * 8;
    u16* lB1 = Bs + (256 + wv * 64) * 8;
    const u16* a0 = A + (m0 + r0) * (long)K + b0;
    const u16* a1 = A + (m0 + r1) * (long)K + b0;
    const u16* w0 = W + (long)(n0 + r0) * K + b0;
    const u16* w1 = W + (long)(n0 + r1) * K + b0;

    for (int k0 = 0; k0 < K; k0 += 32) {
        __syncthreads();
        async16(a0 + k0, lA0);
        async16(a1 + k0, lA1);
        async16(w0 + k0, lB0);
        async16(w1 + k0, lB1);
        __syncthreads();
        short8 af[4], bf[4];
#pragma unroll
        for (int i = 0; i < 4; i++) af[i] = *(const short8*)(As + (wm + i * 16 + lr) * 32 + q4 * 8);
#pragma unroll
        for (int j = 0; j < 4; j++) bf[j] = *(const short8*)(Bs + (wn + j * 16 + lr) * 32 + q4 * 8);
#pragma unroll
        for (int i = 0; i < 4; i++)
#pragma unroll
            for (int j = 0; j < 4; j++)
                acc[i][j] = __builtin_amdgcn_mfma_f32_16x16x32_bf16(af[i], bf[j], acc[i][j], 0, 0, 0);
    }

    // epilogue: C row = quad*4+reg, col = lane&15
#pragma unroll
    for (int i = 0; i < 4; i++) {
#pragma unroll
        for (int j = 0; j < 4; j++) {
            const int gn = n0 + wn + j * 16 + lr;
#pragma unroll
            for (int r = 0; r < 4; r++) {
                const long gm = m0 + wm + i * 16 + q4 * 4 + r;
                float v = acc[i][j][r];
                if constexpr (MODE == M_QKV) {
                    v = (v + bias[gn]) * scale;
                    ((u16*)out)[gm * N + gn] = f2bf(v);
                } else if constexpr (MODE == M_VT) {
                    v = v + bias[gm];
                    const long b = gn >> 11, s = gn & 2047;
                    ((u16*)out)[(b << 22) + gm * 2048 + s] = f2bf(v);
                } else if constexpr (MODE == M_H1) {
                    ((float*)out)[gm * N + gn] = v + bias[gn] + resid[gm * N + gn];
                } else if constexpr (MODE == M_RELU) {
                    ((u16*)out)[gm * N + gn] = f2bf(fmaxf(v, 0.0f));
                } else if constexpr (MODE == M_MUL) {
                    ((u16*)out)[gm * N + gn] = f2bf(v * bf2f(aux[gm * N + gn]));
                } else {  // M_ADD
                    ((float*)out)[gm * N + gn] = v + resid[gm * N + gn];
                }
            }
        }
    }
}

// ---------------- flash attention, computes O^T directly into the scrambled layout ----------------
// Q,K: [4096][2048] bf16 (rows b*2048+s, head slice at h*128). Vt: [b][h*128+d][s] bf16.
// Out scr[b][h*128+d][s] = softmax(QK^T/sqrt(128)) @ V, transposed. Scale folded into Q.
// Ks/Vs use a 16B-chunk XOR swizzle: physical chunk p of row r holds logical chunk p^(r&15).
// This spreads the quad-uniform fragment reads across all 32 banks (8 dwords/bank = b128 min)
// instead of 16-way conflicting on 4 banks (row pitch 256B is bank-invariant).
__global__ __launch_bounds__(512) void attn_kernel(const u16* __restrict__ Q, const u16* __restrict__ Km,
                                                   const u16* __restrict__ Vt, u16* __restrict__ Oscr) {
    __shared__ u16 Ks[128 * 128];
    __shared__ u16 Vs[128 * 128];
    __shared__ u16 Ps[8][16 * 136];  // per-wave P strip, pitch 136 (8/bank on b128 reads)
    __shared__ float abuf[8][16];
    __shared__ float lbuf[8][16];
    const int tid = threadIdx.x, w = tid >> 6, lane = tid & 63;
    const int q4 = lane >> 4, lr = lane & 15;
    const int bh = blockIdx.y, b = bh >> 4, h = bh & 15;
    const int sw = blockIdx.x * 128 + w * 16;  // this wave's 16 query rows
    const long qkbase = ((long)b * 2048) * 2048 + h * 128;
    const long vtbase = ((long)b * 2048 + h * 128) * 2048;

    short8 qf[4];
    {
        const u16* qr = Q + qkbase + (long)(sw + lr) * 2048 + q4 * 8;
#pragma unroll
        for (int kk = 0; kk < 4; kk++) qf[kk] = *(const short8*)(qr + kk * 32);
    }
    float m_i[4], l_i[4];
#pragma unroll
    for (int r = 0; r < 4; r++) { m_i[r] = -1e30f; l_i[r] = 0.0f; }
    f32x4 oacc[8] = {};

    for (int t0 = 0; t0 < 2048; t0 += 128) {
        __syncthreads();
#pragma unroll
        for (int i = 0; i < 4; i++) {
            const int c = i * 512 + tid;           // linear 16B chunk 0..2047
            const int row = c >> 4;                // tile row 0..127
            const int lc = (c & 15) ^ (row & 15);  // logical chunk fetched into physical slot
            async16(Km + qkbase + (long)(t0 + row) * 2048 + lc * 8, (u16*)Ks + (i * 512 + w * 64) * 8);
            async16(Vt + vtbase + (long)row * 2048 + t0 + lc * 8, (u16*)Vs + (i * 512 + w * 64) * 8);
        }
        __syncthreads();
        // S strip [16 s][128 t] = q * K^T (scale pre-folded into q)
        f32x4 sacc[8] = {};
#pragma unroll
        for (int kk = 0; kk < 4; kk++) {
#pragma unroll
            for (int n = 0; n < 8; n++) {
                const int pc = (kk * 4 + q4) ^ lr;  // swizzled chunk
                short8 kf = *(const short8*)(Ks + ((n * 16 + lr) * 16 + pc) * 8);
                sacc[n] = __builtin_amdgcn_mfma_f32_16x16x32_bf16(qf[kk], kf, sacc[n], 0, 0, 0);
            }
        }
        // online softmax per s-row (row = q4*4+r, replicated across the 16 lanes of the quad)
        float al[4];
#pragma unroll
        for (int r = 0; r < 4; r++) {
            float mx = sacc[0][r];
#pragma unroll
            for (int n = 1; n < 8; n++) mx = fmaxf(mx, sacc[n][r]);
#pragma unroll
            for (int msk = 1; msk < 16; msk <<= 1) mx = fmaxf(mx, __shfl_xor(mx, msk, 64));
            const float mn = fmaxf(m_i[r], mx);
            al[r] = __expf(m_i[r] - mn);
            float rs = 0.0f;
#pragma unroll
            for (int n = 0; n < 8; n++) {
                float p = __expf(sacc[n][r] - mn);
                sacc[n][r] = p;
                rs += p;
            }
#pragma unroll
            for (int msk = 1; msk < 16; msk <<= 1) rs += __shfl_xor(rs, msk, 64);
            l_i[r] = l_i[r] * al[r] + rs;
            m_i[r] = mn;
        }
        // P -> LDS (bf16), alpha broadcast
#pragma unroll
        for (int n = 0; n < 8; n++)
#pragma unroll
            for (int r = 0; r < 4; r++)
                Ps[w][(q4 * 4 + r) * 136 + n * 16 + lr] = f2bf(sacc[n][r]);
        if (lr == 0) {
#pragma unroll
            for (int r = 0; r < 4; r++) abuf[w][q4 * 4 + r] = al[r];
        }
        __syncthreads();
        const float a_s = abuf[w][lr];
#pragma unroll
        for (int mm = 0; mm < 8; mm++) oacc[mm] *= a_s;
        // O^T[d][s] += Vt_tile(rows d) * P^T : A-frag from Vs rows, B-frag from Ps rows
#pragma unroll
        for (int kk = 0; kk < 4; kk++) {
            short8 pf = *(const short8*)(&Ps[w][lr * 136 + kk * 32 + q4 * 8]);
            const int pc = (kk * 4 + q4) ^ lr;
#pragma unroll
            for (int mm = 0; mm < 8; mm++) {
                short8 vf = *(const short8*)(Vs + ((mm * 16 + lr) * 16 + pc) * 8);
                oacc[mm] = __builtin_amdgcn_mfma_f32_16x16x32_bf16(vf, pf, oacc[mm], 0, 0, 0);
            }
        }
    }
    if (lr == 0) {
#pragma unroll
        for (int r = 0; r < 4; r++) lbuf[w][q4 * 4 + r] = l_i[r];
    }
    __syncthreads();
    const float linv = 1.0f / lbuf[w][lr];
    // write O^T: row d = mm*16+q4*4+r, col s = sw+lr (16-lane contiguous bf16 stores)
#pragma unroll
    for (int mm = 0; mm < 8; mm++) {
#pragma unroll
        for (int r = 0; r < 4; r++) {
            const int d = mm * 16 + q4 * 4 + r;
            Oscr[vtbase + (long)d * 2048 + sw + lr] = f2bf(oacc[mm][r] * linv);
        }
    }
}

// ---------------- launch ----------------
// Workspace budget (112 MB total), lifetime-aliased:
//   [0,16)MB   : xn  -> scr -> hn      (sequential lives)
//   [16,80)MB  : qb|kb|vt (16 each) -> grelu (64) -> inter (in-place)
//   [80,112)MB : JIT bf16 weight region: {wq,wk,wv,wo} -> wg -> wu -> wd
//   h1 lives in d_out (fp32, fully overwritten before first read).
extern "C" void kernel_launch(void* const* d_in, const int* in_sizes, int n_in,
                              void* d_out, int out_size, void* d_ws, size_t ws_size,
                              hipStream_t stream) {
    const float* x  = (const float*)d_in[0];
    const float* wq = (const float*)d_in[1];
    const float* bq = (const float*)d_in[2];
    const float* wk = (const float*)d_in[3];
    const float* bk = (const float*)d_in[4];
    const float* wv = (const float*)d_in[5];
    const float* bv = (const float*)d_in[6];
    const float* wo = (const float*)d_in[7];
    const float* bo = (const float*)d_in[8];
    const float* wg = (const float*)d_in[9];
    const float* wu = (const float*)d_in[10];
    const float* wd = (const float*)d_in[11];
    const float* ga = (const float*)d_in[12];
    const float* gf = (const float*)d_in[13];

    char* ws = (char*)d_ws;
    const size_t MB = (size_t)1 << 20;
    u16*  xn    = (u16*)(ws + 0);
    u16*  scr   = (u16*)(ws + 0);            // alias: xn dead after projections
    u16*  hn    = (u16*)(ws + 0);            // alias: scr dead after o-proj
    u16*  qb    = (u16*)(ws + 16 * MB);
    u16*  kb    = (u16*)(ws + 32 * MB);
    u16*  vt    = (u16*)(ws + 48 * MB);
    u16*  grelu = (u16*)(ws + 16 * MB);      // 64 MB, alias over qb/kb/vt/pad
    u16*  inter = grelu;                     // in-place relu(g)*u
    u16*  wreg  = (u16*)(ws + 80 * MB);      // 32 MB JIT weight region
    u16*  wq_b  = wreg;
    u16*  wk_b  = wreg + 4 * MB;             // u16 elements: 8MB bytes each
    u16*  wv_b  = wreg + 8 * MB;
    u16*  wo_b  = wreg + 12 * MB;
    u16*  wbig  = wreg;                      // wg -> wu -> wd reuse
    float* h1   = (float*)d_out;

    // phase-A weights fp32 -> bf16
    cvt_k<<<4096, 256, 0, stream>>>(wq, wq_b);
    cvt_k<<<4096, 256, 0, stream>>>(wk, wk_b);
    cvt_k<<<4096, 256, 0, stream>>>(wv, wv_b);
    cvt_k<<<4096, 256, 0, stream>>>(wo, wo_b);

    rmsnorm_k<<<4096, 256, 0, stream>>>(x, ga, xn);

    const float qscale = 0.08838834764831843f;  // 1/sqrt(128)
    gemm_bt<M_QKV><<<dim3(16, 32), 256, 0, stream>>>(xn, wq_b, bq, nullptr, nullptr, qb, 2048, 2048, qscale);
    gemm_bt<M_QKV><<<dim3(16, 32), 256, 0, stream>>>(xn, wk_b, bk, nullptr, nullptr, kb, 2048, 2048, 1.0f);
    // V^T: roles swapped -> C[nv][(b,s)] = wv . xn^T, stored [b][nv][s]
    gemm_bt<M_VT><<<dim3(32, 16), 256, 0, stream>>>(wv_b, xn, bv, nullptr, nullptr, vt, 4096, 2048, 1.0f);

    attn_kernel<<<dim3(16, 32), 512, 0, stream>>>(qb, kb, vt, scr);

    // out-proj + residual: h1 = x + scr @ wo^T + bo   (h1 lives in d_out)
    gemm_bt<M_H1><<<dim3(16, 32), 256, 0, stream>>>(scr, wo_b, bo, x, nullptr, h1, 2048, 2048, 1.0f);

    cvt_k<<<16384, 256, 0, stream>>>(wg, wbig);          // wq..wo dead now
    rmsnorm_k<<<4096, 256, 0, stream>>>(h1, gf, hn);

    gemm_bt<M_RELU><<<dim3(64, 32), 256, 0, stream>>>(hn, wbig, nullptr, nullptr, nullptr, grelu, 8192, 2048, 1.0f);

    cvt_k<<<16384, 256, 0, stream>>>(wu, wbig);          // wg dead
    gemm_bt<M_MUL><<<dim3(64, 32), 256, 0, stream>>>(hn, wbig, nullptr, nullptr, grelu, inter, 8192, 2048, 1.0f);

    cvt_k<<<16384, 256, 0, stream>>>(wd, wbig);          // wu dead
    gemm_bt<M_ADD><<<dim3(16, 32), 256, 0, stream>>>(inter, wbig, nullptr, h1, nullptr, d_out, 2048, 8192, 1.0f);
}